// Round 1
// baseline (640.239 us; speedup 1.0000x reference)
//
#include <hip/hip_runtime.h>

// relationalGraphStack on MI355X — round 0 (correctness-first, restructured algorithm)
// Pipeline: zero -> count(deg,cnt) -> scan(CSR) -> fill(ebuf,ew)
//   -> gemm(y1 in d_out, s1) -> gather1(h_pre + stats) -> bnstats1 -> bnrelu(h)
//   -> gemm(z, s2) -> gather2(out_pre in d_out + stats) -> bnstats2 -> bnrelu(out)

#define GATHER_GRID 2048

__global__ void k_zero(float* __restrict__ deg, int* __restrict__ cnt, int ndeg, int ncnt) {
  int i = blockIdx.x * blockDim.x + threadIdx.x;
  int stride = gridDim.x * blockDim.x;
  for (int k = i; k < ndeg; k += stride) deg[k] = 0.f;
  for (int k = i; k < ncnt; k += stride) cnt[k] = 0;
}

__global__ void k_count(const float* __restrict__ w, const int* __restrict__ node_out,
                        const int* __restrict__ rel, float* __restrict__ deg,
                        int* __restrict__ cnt, int E, int R) {
  int i = blockIdx.x * blockDim.x + threadIdx.x;
  int stride = gridDim.x * blockDim.x;
  for (int e = i; e < E; e += stride) {
    int no = node_out[e];
    atomicAdd(&deg[no * R + rel[e]], w[e]);
    atomicAdd(&cnt[no], 1);
  }
}

// single-block scan over cnt[0..N) -> exclusive rowptr (and wptr copy)
__global__ void k_scan(const int* __restrict__ cnt, int* __restrict__ rowptr,
                       int* __restrict__ wptr, int N) {
  __shared__ int wsum[16];
  __shared__ int wincl[16];
  __shared__ int carry;
  int tid = threadIdx.x, lane = tid & 63, wid = tid >> 6;
  if (tid == 0) carry = 0;
  __syncthreads();
  for (int base = 0; base < N; base += 1024) {
    int i = base + tid;
    int v = (i < N) ? cnt[i] : 0;
    int incl = v;
    #pragma unroll
    for (int off = 1; off < 64; off <<= 1) {
      int t = __shfl_up(incl, off);
      if (lane >= off) incl += t;
    }
    if (lane == 63) wsum[wid] = incl;
    __syncthreads();
    if (tid < 16) {
      int t = wsum[tid];
      #pragma unroll
      for (int off = 1; off < 16; off <<= 1) {
        int u = __shfl_up(t, off);
        if (tid >= (unsigned)off) t += u;
      }
      wincl[tid] = t;
    }
    __syncthreads();
    int excl = carry + (wid > 0 ? wincl[wid - 1] : 0) + incl - v;
    if (i < N) { rowptr[i] = excl; wptr[i] = excl; }
    __syncthreads();
    if (tid == 0) carry += wincl[15];
    __syncthreads();
  }
  if (tid == 0) rowptr[N] = carry;
}

__global__ void k_fill(const float* __restrict__ w, const int* __restrict__ node_out,
                       const int* __restrict__ rel, const float* __restrict__ deg,
                       int* __restrict__ wptr, int* __restrict__ ebuf,
                       float* __restrict__ ew, int E, int R) {
  int i = blockIdx.x * blockDim.x + threadIdx.x;
  int stride = gridDim.x * blockDim.x;
  for (int e = i; e < E; e += stride) {
    int no = node_out[e];
    int pos = atomicAdd(&wptr[no], 1);
    ebuf[pos] = e;
    ew[e] = w[e] / deg[no * R + rel[e]];
  }
}

// out[m,j] = sum_d x[m,d] * W[j, off+d].  blockIdx.y selects slab:
//   y < nslab : W=Wlin (stride wlinStride), off=y*64, outp = outLin + y*N*64
//   y == nslab: W=Wself (stride 64), off=0, outp = outSelf
__global__ __launch_bounds__(256) void k_gemm64(
    const float* __restrict__ x, int N,
    const float* __restrict__ Wlin, int wlinStride, int nslab,
    const float* __restrict__ Wself,
    float* __restrict__ outLin, float* __restrict__ outSelf) {
  __shared__ float xs[64][65];
  __shared__ float wl[64][65];
  int slab = blockIdx.y;
  const float* W; int wstride, off; float* outp;
  if (slab < nslab) { W = Wlin; wstride = wlinStride; off = slab * 64; outp = outLin + (size_t)slab * N * 64; }
  else             { W = Wself; wstride = 64;        off = 0;         outp = outSelf; }
  int m0 = blockIdx.x * 64;
  int t = threadIdx.x;
  #pragma unroll
  for (int i = 0; i < 16; i++) {
    int lin = t + i * 256;
    int m = lin >> 6, d = lin & 63;
    xs[m][d] = (m0 + m < N) ? x[(size_t)(m0 + m) * 64 + d] : 0.f;
  }
  #pragma unroll
  for (int i = 0; i < 16; i++) {
    int lin = t + i * 256;
    int j = lin >> 6, d = lin & 63;
    wl[d][j] = W[(size_t)j * wstride + off + d];
  }
  __syncthreads();
  int ti = t & 15, tj = t >> 4;
  float acc[4][4] = {};
  for (int d = 0; d < 64; d++) {
    float a[4], b[4];
    #pragma unroll
    for (int q = 0; q < 4; q++) a[q] = xs[ti * 4 + q][d];
    #pragma unroll
    for (int p = 0; p < 4; p++) b[p] = wl[d][tj * 4 + p];
    #pragma unroll
    for (int q = 0; q < 4; q++)
      #pragma unroll
      for (int p = 0; p < 4; p++) acc[q][p] += a[q] * b[p];
  }
  #pragma unroll
  for (int q = 0; q < 4; q++) {
    int m = m0 + ti * 4 + q;
    if (m < N) {
      float4 vv = make_float4(acc[q][0], acc[q][1], acc[q][2], acc[q][3]);
      *(float4*)&outp[(size_t)m * 64 + tj * 4] = vv;
    }
  }
}

// layer1 gather: h_pre[n,j] = s1[n,j] + sum_{e->n} ew_e * y1[rel_e, src_e, j]
__global__ __launch_bounds__(256) void k_gather1(
    const int* __restrict__ rowptr, const int* __restrict__ ebuf,
    const int* __restrict__ node_in, const int* __restrict__ rel,
    const float* __restrict__ ew, const float* __restrict__ y1,
    const float* __restrict__ s1, float* __restrict__ h,
    float* __restrict__ part, int N) {
  int lane = threadIdx.x & 63;
  int wid = threadIdx.x >> 6;
  int gw = blockIdx.x * 4 + wid;
  int nw = gridDim.x * 4;
  float lsum = 0.f, lsq = 0.f;
  for (int n = gw; n < N; n += nw) {
    float acc = s1[(size_t)n * 64 + lane];
    int k = rowptr[n], kend = rowptr[n + 1];
    while (k < kend) {
      int cnt = kend - k; if (cnt > 64) cnt = 64;
      int e = (lane < cnt) ? ebuf[k + lane] : 0;
      int srcl = 0, rell = 0; float wl_ = 0.f;
      if (lane < cnt) { srcl = node_in[e]; rell = rel[e]; wl_ = ew[e]; }
      for (int tt = 0; tt < cnt; tt++) {
        int src = __shfl(srcl, tt);
        int rr = __shfl(rell, tt);
        float wgt = __shfl(wl_, tt);
        acc += wgt * y1[((size_t)rr * N + src) * 64 + lane];
      }
      k += cnt;
    }
    h[(size_t)n * 64 + lane] = acc;
    lsum += acc; lsq += acc * acc;
  }
  __shared__ float sp[4][64], sq2[4][64];
  sp[wid][lane] = lsum; sq2[wid][lane] = lsq;
  __syncthreads();
  if (threadIdx.x < 64) {
    float s = 0.f, q = 0.f;
    for (int w2 = 0; w2 < 4; w2++) { s += sp[w2][threadIdx.x]; q += sq2[w2][threadIdx.x]; }
    part[(size_t)blockIdx.x * 128 + threadIdx.x] = s;
    part[(size_t)blockIdx.x * 128 + 64 + threadIdx.x] = q;
  }
}

// layer2 gather: out_pre[r*N+n, j] = s2[n,j] + sum_{e->n, rel=r} ew_e * z[src_e, j]
__global__ __launch_bounds__(256) void k_gather2(
    const int* __restrict__ rowptr, const int* __restrict__ ebuf,
    const int* __restrict__ node_in, const int* __restrict__ rel,
    const float* __restrict__ ew, const float* __restrict__ z,
    const float* __restrict__ s2, float* __restrict__ out,
    float* __restrict__ part, int N) {
  int lane = threadIdx.x & 63;
  int wid = threadIdx.x >> 6;
  int gw = blockIdx.x * 4 + wid;
  int nw = gridDim.x * 4;
  float lsum = 0.f, lsq = 0.f;
  for (int n = gw; n < N; n += nw) {
    float a0=0,a1=0,a2=0,a3=0,a4=0,a5=0,a6=0,a7=0;
    int k = rowptr[n], kend = rowptr[n + 1];
    while (k < kend) {
      int cnt = kend - k; if (cnt > 64) cnt = 64;
      int e = (lane < cnt) ? ebuf[k + lane] : 0;
      int srcl = 0, rell = 0; float wl_ = 0.f;
      if (lane < cnt) { srcl = node_in[e]; rell = rel[e]; wl_ = ew[e]; }
      for (int tt = 0; tt < cnt; tt++) {
        int src = __shfl(srcl, tt);
        int rr = __shfl(rell, tt);
        float wgt = __shfl(wl_, tt);
        float v = wgt * z[(size_t)src * 64 + lane];
        switch (rr) {
          case 0: a0 += v; break; case 1: a1 += v; break;
          case 2: a2 += v; break; case 3: a3 += v; break;
          case 4: a4 += v; break; case 5: a5 += v; break;
          case 6: a6 += v; break; default: a7 += v; break;
        }
      }
      k += cnt;
    }
    float sv = s2[(size_t)n * 64 + lane];
    float vals[8] = {a0+sv, a1+sv, a2+sv, a3+sv, a4+sv, a5+sv, a6+sv, a7+sv};
    #pragma unroll
    for (int r = 0; r < 8; r++) {
      float v = vals[r];
      out[((size_t)r * N + n) * 64 + lane] = v;
      lsum += v; lsq += v * v;
    }
  }
  __shared__ float sp[4][64], sq2[4][64];
  sp[wid][lane] = lsum; sq2[wid][lane] = lsq;
  __syncthreads();
  if (threadIdx.x < 64) {
    float s = 0.f, q = 0.f;
    for (int w2 = 0; w2 < 4; w2++) { s += sp[w2][threadIdx.x]; q += sq2[w2][threadIdx.x]; }
    part[(size_t)blockIdx.x * 128 + threadIdx.x] = s;
    part[(size_t)blockIdx.x * 128 + 64 + threadIdx.x] = q;
  }
}

// reduce partials -> per-column scale/shift.  block = 1024 threads.
__global__ __launch_bounds__(1024) void k_bnstats(
    const float* __restrict__ part, int P, float M,
    const float* __restrict__ gamma, const float* __restrict__ beta,
    float* __restrict__ ss) {
  __shared__ float red[1024];
  int tid = threadIdx.x;
  int j = tid & 127;
  int g = tid >> 7;
  float acc = 0.f;
  for (int i = g; i < P; i += 8) acc += part[(size_t)i * 128 + j];
  red[tid] = acc;
  __syncthreads();
  if (tid < 128) {
    float s = 0.f;
    for (int gg = 0; gg < 8; gg++) s += red[gg * 128 + tid];
    red[tid] = s;
  }
  __syncthreads();
  if (tid < 64) {
    float s = red[tid], q = red[64 + tid];
    float mean = s / M;
    float var = q / M - mean * mean;
    float sc = gamma[tid] / sqrtf(var + 1e-5f);
    ss[tid] = sc;
    ss[64 + tid] = beta[tid] - mean * sc;
  }
}

__global__ void k_bnrelu4(float4* __restrict__ buf, const float* __restrict__ ss, long total4) {
  __shared__ float s_ss[128];
  if (threadIdx.x < 128) s_ss[threadIdx.x] = ss[threadIdx.x];
  __syncthreads();
  long i = (long)blockIdx.x * blockDim.x + threadIdx.x;
  long stride = (long)gridDim.x * blockDim.x;
  for (long k = i; k < total4; k += stride) {
    float4 v = buf[k];
    int j0 = ((int)k & 15) * 4;
    v.x = fmaxf(fmaf(v.x, s_ss[j0 + 0], s_ss[64 + j0 + 0]), 0.f);
    v.y = fmaxf(fmaf(v.y, s_ss[j0 + 1], s_ss[64 + j0 + 1]), 0.f);
    v.z = fmaxf(fmaf(v.z, s_ss[j0 + 2], s_ss[64 + j0 + 2]), 0.f);
    v.w = fmaxf(fmaf(v.w, s_ss[j0 + 3], s_ss[64 + j0 + 3]), 0.f);
    buf[k] = v;
  }
}

extern "C" void kernel_launch(void* const* d_in, const int* in_sizes, int n_in,
                              void* d_out, int out_size, void* d_ws, size_t ws_size,
                              hipStream_t stream) {
  const float* x        = (const float*)d_in[0];
  const float* edge_w   = (const float*)d_in[1];
  const float* W_lin1   = (const float*)d_in[2];
  const float* W_self1  = (const float*)d_in[4];
  const float* gamma1   = (const float*)d_in[6];
  const float* beta1    = (const float*)d_in[7];
  const float* W_lin2   = (const float*)d_in[8];
  const float* W_self2  = (const float*)d_in[10];
  const float* gamma2   = (const float*)d_in[12];
  const float* beta2    = (const float*)d_in[13];
  const int* node_in    = (const int*)d_in[14];
  const int* node_out   = (const int*)d_in[15];
  const int* relation   = (const int*)d_in[16];

  int N = in_sizes[0] / 64;           // 50000
  int E = in_sizes[1];                // 800000
  int R = in_sizes[2] / (64 * 64);    // 8

  char* p = (char*)d_ws;
  auto alloc = [&](size_t bytes) { char* r = p; p += (bytes + 255) & ~(size_t)255; return r; };
  float* deg   = (float*)alloc(4ull * N * R);
  float* ew    = (float*)alloc(4ull * E);
  int* cnt     = (int*)alloc(4ull * N);
  int* rowptr  = (int*)alloc(4ull * (N + 1));
  int* wptr    = (int*)alloc(4ull * N);
  int* ebuf    = (int*)alloc(4ull * E);
  float* s1    = (float*)alloc(4ull * N * 64);
  float* h     = (float*)alloc(4ull * N * 64);
  float* z     = (float*)alloc(4ull * N * 64);
  float* s2    = (float*)alloc(4ull * N * 64);
  float* part1 = (float*)alloc(4ull * GATHER_GRID * 128);
  float* part2 = (float*)alloc(4ull * GATHER_GRID * 128);
  float* ss1   = (float*)alloc(4ull * 128);
  float* ss2   = (float*)alloc(4ull * 128);
  float* y1    = (float*)d_out;  // 102.4MB scratch lives in d_out until gather1 consumes it

  k_zero<<<512, 256, 0, stream>>>(deg, cnt, N * R, N);
  k_count<<<1024, 256, 0, stream>>>(edge_w, node_out, relation, deg, cnt, E, R);
  k_scan<<<1, 1024, 0, stream>>>(cnt, rowptr, wptr, N);
  k_fill<<<1024, 256, 0, stream>>>(edge_w, node_out, relation, deg, wptr, ebuf, ew, E, R);

  // layer 1: y1[r] = x @ W_r^T (into d_out), s1 = x @ W_self1^T
  dim3 g1((N + 63) / 64, R + 1);
  k_gemm64<<<g1, 256, 0, stream>>>(x, N, W_lin1, R * 64, R, W_self1, y1, s1);
  k_gather1<<<GATHER_GRID, 256, 0, stream>>>(rowptr, ebuf, node_in, relation, ew, y1, s1, h, part1, N);
  k_bnstats<<<1, 1024, 0, stream>>>(part1, GATHER_GRID, (float)N, gamma1, beta1, ss1);
  k_bnrelu4<<<2048, 256, 0, stream>>>((float4*)h, ss1, (long)N * 64 / 4);

  // layer 2: z = h @ W_lin2^T, s2 = h @ W_self2^T
  dim3 g2((N + 63) / 64, 2);
  k_gemm64<<<g2, 256, 0, stream>>>(h, N, W_lin2, 64, 1, W_self2, z, s2);
  k_gather2<<<GATHER_GRID, 256, 0, stream>>>(rowptr, ebuf, node_in, relation, ew, z, s2, (float*)d_out, part2, N);
  k_bnstats<<<1, 1024, 0, stream>>>(part2, GATHER_GRID, (float)N * R, gamma2, beta2, ss2);
  k_bnrelu4<<<4096, 256, 0, stream>>>((float4*)d_out, ss2, (long)N * R * 64 / 4);
}

// Round 2
// 581.930 us; speedup vs baseline: 1.1002x; 1.1002x over previous
//
#include <hip/hip_runtime.h>

// relationalGraphStack — round 1
// Changes vs R0:
//  - CSR keyed by seg = node*R + rel (400k segments): rel implicit per segment,
//    edge payload packed int2{src, weight} -> no switch in gather2, 1 load/edge.
//  - y1 and z stored bf16 (halves gather read traffic; z now 6.4MB -> L2-friendlier).
//  - multi-block scan (count -> blocksum -> scan -> chunk-scan) replaces 1-block scan.

#define GATHER_GRID 2048
#define SCAN_CHUNK 4096

static __device__ __forceinline__ float bf2f(unsigned short u) {
  return __uint_as_float(((unsigned)u) << 16);
}
static __device__ __forceinline__ unsigned short f2bf(float f) {
  unsigned u = __float_as_uint(f);
  u += 0x7FFFu + ((u >> 16) & 1u);  // round to nearest even
  return (unsigned short)(u >> 16);
}

__global__ void k_zero(float* __restrict__ deg, int* __restrict__ cnt, int n) {
  int i = blockIdx.x * blockDim.x + threadIdx.x;
  int stride = gridDim.x * blockDim.x;
  for (int k = i; k < n; k += stride) { deg[k] = 0.f; cnt[k] = 0; }
}

__global__ void k_count(const float* __restrict__ w, const int* __restrict__ node_out,
                        const int* __restrict__ rel, float* __restrict__ deg,
                        int* __restrict__ cnt, int E, int R) {
  int i = blockIdx.x * blockDim.x + threadIdx.x;
  int stride = gridDim.x * blockDim.x;
  for (int e = i; e < E; e += stride) {
    int seg = node_out[e] * R + rel[e];
    atomicAdd(&deg[seg], w[e]);
    atomicAdd(&cnt[seg], 1);
  }
}

// block sums of cnt in SCAN_CHUNK chunks
__global__ __launch_bounds__(256) void k_scan1(const int* __restrict__ cnt,
                                               int* __restrict__ bsum, int NR) {
  __shared__ int red[256];
  int tid = threadIdx.x;
  int base = blockIdx.x * SCAN_CHUNK;
  int s = 0;
  for (int i = tid; i < SCAN_CHUNK; i += 256) {
    int idx = base + i;
    if (idx < NR) s += cnt[idx];
  }
  red[tid] = s;
  __syncthreads();
  for (int off = 128; off > 0; off >>= 1) {
    if (tid < off) red[tid] += red[tid + off];
    __syncthreads();
  }
  if (tid == 0) bsum[blockIdx.x] = red[0];
}

// exclusive scan of bsum (single 64-thread wave)
__global__ void k_scan2(const int* __restrict__ bsum, int* __restrict__ bpre,
                        int* __restrict__ rowptr_end, int NB) {
  int lane = threadIdx.x;
  int carry = 0;
  for (int base = 0; base < NB; base += 64) {
    int i = base + lane;
    int v = (i < NB) ? bsum[i] : 0;
    int incl = v;
    #pragma unroll
    for (int off = 1; off < 64; off <<= 1) {
      int u = __shfl_up(incl, off);
      if (lane >= off) incl += u;
    }
    if (i < NB) bpre[i] = carry + incl - v;
    carry += __shfl(incl, 63);
  }
  if (lane == 0) *rowptr_end = carry;
}

// per-chunk exclusive scan with block offset -> rowptr, wptr
__global__ __launch_bounds__(256) void k_scan3(const int* __restrict__ cnt,
                                               const int* __restrict__ bpre,
                                               int* __restrict__ rowptr,
                                               int* __restrict__ wptr, int NR) {
  __shared__ int wtot[4];
  int tid = threadIdx.x, lane = tid & 63, wid = tid >> 6;
  int base = blockIdx.x * SCAN_CHUNK + tid * 16;
  int v[16];
  int t = 0;
  #pragma unroll
  for (int i = 0; i < 16; i++) {
    int idx = base + i;
    v[i] = (idx < NR) ? cnt[idx] : 0;
    t += v[i];
  }
  int incl = t;
  #pragma unroll
  for (int off = 1; off < 64; off <<= 1) {
    int u = __shfl_up(incl, off);
    if (lane >= off) incl += u;
  }
  if (lane == 63) wtot[wid] = incl;
  __syncthreads();
  int woff = 0;
  for (int w = 0; w < wid; w++) woff += wtot[w];
  int start = bpre[blockIdx.x] + woff + incl - t;
  #pragma unroll
  for (int i = 0; i < 16; i++) {
    int idx = base + i;
    if (idx < NR) { rowptr[idx] = start; wptr[idx] = start; }
    start += v[i];
  }
}

__global__ void k_fill(const float* __restrict__ w, const int* __restrict__ node_out,
                       const int* __restrict__ node_in, const int* __restrict__ rel,
                       const float* __restrict__ deg, int* __restrict__ wptr,
                       int2* __restrict__ ep, int E, int R) {
  int i = blockIdx.x * blockDim.x + threadIdx.x;
  int stride = gridDim.x * blockDim.x;
  for (int e = i; e < E; e += stride) {
    int seg = node_out[e] * R + rel[e];
    int pos = atomicAdd(&wptr[seg], 1);
    float v = w[e] / deg[seg];
    ep[pos] = make_int2(node_in[e], __float_as_int(v));
  }
}

// out[m,j] = sum_d x[m,d] * W[j, off+d].  lin slabs -> bf16 out, self slab -> f32 out.
__global__ __launch_bounds__(256) void k_gemm64(
    const float* __restrict__ x, int N,
    const float* __restrict__ Wlin, int wlinStride, int nslab,
    const float* __restrict__ Wself,
    unsigned short* __restrict__ outLinB, float* __restrict__ outSelf) {
  __shared__ float xs[64][65];
  __shared__ float wl[64][65];
  int slab = blockIdx.y;
  const float* W; int wstride, off;
  if (slab < nslab) { W = Wlin; wstride = wlinStride; off = slab * 64; }
  else             { W = Wself; wstride = 64;        off = 0; }
  int m0 = blockIdx.x * 64;
  int t = threadIdx.x;
  #pragma unroll
  for (int i = 0; i < 16; i++) {
    int lin = t + i * 256;
    int m = lin >> 6, d = lin & 63;
    xs[m][d] = (m0 + m < N) ? x[(size_t)(m0 + m) * 64 + d] : 0.f;
  }
  #pragma unroll
  for (int i = 0; i < 16; i++) {
    int lin = t + i * 256;
    int j = lin >> 6, d = lin & 63;
    wl[d][j] = W[(size_t)j * wstride + off + d];
  }
  __syncthreads();
  int ti = t & 15, tj = t >> 4;
  float acc[4][4] = {};
  for (int d = 0; d < 64; d++) {
    float a[4], b[4];
    #pragma unroll
    for (int q = 0; q < 4; q++) a[q] = xs[ti * 4 + q][d];
    #pragma unroll
    for (int p = 0; p < 4; p++) b[p] = wl[d][tj * 4 + p];
    #pragma unroll
    for (int q = 0; q < 4; q++)
      #pragma unroll
      for (int p = 0; p < 4; p++) acc[q][p] += a[q] * b[p];
  }
  #pragma unroll
  for (int q = 0; q < 4; q++) {
    int m = m0 + ti * 4 + q;
    if (m >= N) continue;
    if (slab < nslab) {
      ushort4 o;
      o.x = f2bf(acc[q][0]); o.y = f2bf(acc[q][1]);
      o.z = f2bf(acc[q][2]); o.w = f2bf(acc[q][3]);
      *(ushort4*)&outLinB[((size_t)slab * N + m) * 64 + tj * 4] = o;
    } else {
      float4 vv = make_float4(acc[q][0], acc[q][1], acc[q][2], acc[q][3]);
      *(float4*)&outSelf[(size_t)m * 64 + tj * 4] = vv;
    }
  }
}

// layer1: h_pre[n,j] = s1[n,j] + sum_r sum_{e in seg(n,r)} w_e * y1[r, src_e, j]
__global__ __launch_bounds__(256) void k_gather1(
    const int* __restrict__ rowptr, const int2* __restrict__ ep,
    const unsigned short* __restrict__ y1, const float* __restrict__ s1,
    float* __restrict__ h, float* __restrict__ part, int N, int R) {
  int lane = threadIdx.x & 63;
  int wid = threadIdx.x >> 6;
  int gw = blockIdx.x * 4 + wid;
  int nw = gridDim.x * 4;
  float lsum = 0.f, lsq = 0.f;
  for (int n = gw; n < N; n += nw) {
    float acc = s1[(size_t)n * 64 + lane];
    int segbase = n * R;
    int k = rowptr[segbase];
    for (int r = 0; r < R; r++) {
      int kend = rowptr[segbase + r + 1];
      const unsigned short* yb = y1 + (size_t)r * N * 64;
      while (k < kend) {
        int cnt = kend - k; if (cnt > 64) cnt = 64;
        int2 v = (lane < cnt) ? ep[k + lane] : make_int2(0, 0);
        for (int tt = 0; tt < cnt; tt++) {
          int src = __shfl(v.x, tt);
          float wgt = __int_as_float(__shfl(v.y, tt));
          acc += wgt * bf2f(yb[(size_t)src * 64 + lane]);
        }
        k = (cnt == 64) ? k + 64 : kend;
      }
    }
    h[(size_t)n * 64 + lane] = acc;
    lsum += acc; lsq += acc * acc;
  }
  __shared__ float sp[4][64], sq2[4][64];
  sp[wid][lane] = lsum; sq2[wid][lane] = lsq;
  __syncthreads();
  if (threadIdx.x < 64) {
    float s = 0.f, q = 0.f;
    for (int w2 = 0; w2 < 4; w2++) { s += sp[w2][threadIdx.x]; q += sq2[w2][threadIdx.x]; }
    part[(size_t)blockIdx.x * 128 + threadIdx.x] = s;
    part[(size_t)blockIdx.x * 128 + 64 + threadIdx.x] = q;
  }
}

// layer2: out[r*N+n, j] = s2[n,j] + sum_{e in seg(n,r)} w_e * z[src_e, j]
__global__ __launch_bounds__(256) void k_gather2(
    const int* __restrict__ rowptr, const int2* __restrict__ ep,
    const unsigned short* __restrict__ z, const float* __restrict__ s2,
    float* __restrict__ out, float* __restrict__ part, int N, int R) {
  int lane = threadIdx.x & 63;
  int wid = threadIdx.x >> 6;
  int gw = blockIdx.x * 4 + wid;
  int nw = gridDim.x * 4;
  float lsum = 0.f, lsq = 0.f;
  for (int n = gw; n < N; n += nw) {
    float sv = s2[(size_t)n * 64 + lane];
    int segbase = n * R;
    int k = rowptr[segbase];
    for (int r = 0; r < R; r++) {
      int kend = rowptr[segbase + r + 1];
      float acc = 0.f;
      while (k < kend) {
        int cnt = kend - k; if (cnt > 64) cnt = 64;
        int2 v = (lane < cnt) ? ep[k + lane] : make_int2(0, 0);
        for (int tt = 0; tt < cnt; tt++) {
          int src = __shfl(v.x, tt);
          float wgt = __int_as_float(__shfl(v.y, tt));
          acc += wgt * bf2f(z[(size_t)src * 64 + lane]);
        }
        k = (cnt == 64) ? k + 64 : kend;
      }
      float val = acc + sv;
      out[((size_t)r * N + n) * 64 + lane] = val;
      lsum += val; lsq += val * val;
    }
  }
  __shared__ float sp[4][64], sq2[4][64];
  sp[wid][lane] = lsum; sq2[wid][lane] = lsq;
  __syncthreads();
  if (threadIdx.x < 64) {
    float s = 0.f, q = 0.f;
    for (int w2 = 0; w2 < 4; w2++) { s += sp[w2][threadIdx.x]; q += sq2[w2][threadIdx.x]; }
    part[(size_t)blockIdx.x * 128 + threadIdx.x] = s;
    part[(size_t)blockIdx.x * 128 + 64 + threadIdx.x] = q;
  }
}

__global__ __launch_bounds__(1024) void k_bnstats(
    const float* __restrict__ part, int P, float M,
    const float* __restrict__ gamma, const float* __restrict__ beta,
    float* __restrict__ ss) {
  __shared__ float red[1024];
  int tid = threadIdx.x;
  int j = tid & 127;
  int g = tid >> 7;
  float acc = 0.f;
  for (int i = g; i < P; i += 8) acc += part[(size_t)i * 128 + j];
  red[tid] = acc;
  __syncthreads();
  if (tid < 128) {
    float s = 0.f;
    for (int gg = 0; gg < 8; gg++) s += red[gg * 128 + tid];
    red[tid] = s;
  }
  __syncthreads();
  if (tid < 64) {
    float s = red[tid], q = red[64 + tid];
    float mean = s / M;
    float var = q / M - mean * mean;
    float sc = gamma[tid] / sqrtf(var + 1e-5f);
    ss[tid] = sc;
    ss[64 + tid] = beta[tid] - mean * sc;
  }
}

__global__ void k_bnrelu4(float4* __restrict__ buf, const float* __restrict__ ss, long total4) {
  __shared__ float s_ss[128];
  if (threadIdx.x < 128) s_ss[threadIdx.x] = ss[threadIdx.x];
  __syncthreads();
  long i = (long)blockIdx.x * blockDim.x + threadIdx.x;
  long stride = (long)gridDim.x * blockDim.x;
  for (long k = i; k < total4; k += stride) {
    float4 v = buf[k];
    int j0 = ((int)k & 15) * 4;
    v.x = fmaxf(fmaf(v.x, s_ss[j0 + 0], s_ss[64 + j0 + 0]), 0.f);
    v.y = fmaxf(fmaf(v.y, s_ss[j0 + 1], s_ss[64 + j0 + 1]), 0.f);
    v.z = fmaxf(fmaf(v.z, s_ss[j0 + 2], s_ss[64 + j0 + 2]), 0.f);
    v.w = fmaxf(fmaf(v.w, s_ss[j0 + 3], s_ss[64 + j0 + 3]), 0.f);
    buf[k] = v;
  }
}

extern "C" void kernel_launch(void* const* d_in, const int* in_sizes, int n_in,
                              void* d_out, int out_size, void* d_ws, size_t ws_size,
                              hipStream_t stream) {
  const float* x        = (const float*)d_in[0];
  const float* edge_w   = (const float*)d_in[1];
  const float* W_lin1   = (const float*)d_in[2];
  const float* W_self1  = (const float*)d_in[4];
  const float* gamma1   = (const float*)d_in[6];
  const float* beta1    = (const float*)d_in[7];
  const float* W_lin2   = (const float*)d_in[8];
  const float* W_self2  = (const float*)d_in[10];
  const float* gamma2   = (const float*)d_in[12];
  const float* beta2    = (const float*)d_in[13];
  const int* node_in    = (const int*)d_in[14];
  const int* node_out   = (const int*)d_in[15];
  const int* relation   = (const int*)d_in[16];

  int N = in_sizes[0] / 64;           // 50000
  int E = in_sizes[1];                // 800000
  int R = in_sizes[2] / (64 * 64);    // 8
  int NR = N * R;                     // 400000
  int NB = (NR + SCAN_CHUNK - 1) / SCAN_CHUNK;  // 98

  char* p = (char*)d_ws;
  auto alloc = [&](size_t bytes) { char* r = p; p += (bytes + 255) & ~(size_t)255; return r; };
  float* deg    = (float*)alloc(4ull * NR);
  int* cnt      = (int*)alloc(4ull * NR);
  int* rowptr   = (int*)alloc(4ull * (NR + 1));
  int* wptr     = (int*)alloc(4ull * NR);
  int* bsum     = (int*)alloc(4ull * NB);
  int* bpre     = (int*)alloc(4ull * NB);
  int2* ep      = (int2*)alloc(8ull * E);
  float* s1     = (float*)alloc(4ull * N * 64);
  float* h      = (float*)alloc(4ull * N * 64);
  unsigned short* z = (unsigned short*)alloc(2ull * N * 64);
  float* s2     = (float*)alloc(4ull * N * 64);
  float* part1  = (float*)alloc(4ull * GATHER_GRID * 128);
  float* part2  = (float*)alloc(4ull * GATHER_GRID * 128);
  float* ss1    = (float*)alloc(4ull * 128);
  float* ss2    = (float*)alloc(4ull * 128);
  unsigned short* y1 = (unsigned short*)d_out;  // 51.2MB bf16 scratch, consumed by gather1

  k_zero<<<512, 256, 0, stream>>>(deg, cnt, NR);
  k_count<<<1024, 256, 0, stream>>>(edge_w, node_out, relation, deg, cnt, E, R);
  k_scan1<<<NB, 256, 0, stream>>>(cnt, bsum, NR);
  k_scan2<<<1, 64, 0, stream>>>(bsum, bpre, &rowptr[NR], NB);
  k_scan3<<<NB, 256, 0, stream>>>(cnt, bpre, rowptr, wptr, NR);
  k_fill<<<1024, 256, 0, stream>>>(edge_w, node_out, node_in, relation, deg, wptr, ep, E, R);

  // layer 1: y1[r] = x @ W_r^T (bf16, in d_out), s1 = x @ W_self1^T
  dim3 g1((N + 63) / 64, R + 1);
  k_gemm64<<<g1, 256, 0, stream>>>(x, N, W_lin1, R * 64, R, W_self1, y1, s1);
  k_gather1<<<GATHER_GRID, 256, 0, stream>>>(rowptr, ep, y1, s1, h, part1, N, R);
  k_bnstats<<<1, 1024, 0, stream>>>(part1, GATHER_GRID, (float)N, gamma1, beta1, ss1);
  k_bnrelu4<<<2048, 256, 0, stream>>>((float4*)h, ss1, (long)N * 64 / 4);

  // layer 2: z = h @ W_lin2^T (bf16), s2 = h @ W_self2^T
  dim3 g2((N + 63) / 64, 2);
  k_gemm64<<<g2, 256, 0, stream>>>(h, N, W_lin2, 64, 1, W_self2, z, s2);
  k_gather2<<<GATHER_GRID, 256, 0, stream>>>(rowptr, ep, z, s2, (float*)d_out, part2, N, R);
  k_bnstats<<<1, 1024, 0, stream>>>(part2, GATHER_GRID, (float)N * R, gamma2, beta2, ss2);
  k_bnrelu4<<<4096, 256, 0, stream>>>((float4*)d_out, ss2, (long)N * R * 64 / 4);
}

// Round 3
// 534.542 us; speedup vs baseline: 1.1977x; 1.0887x over previous
//
#include <hip/hip_runtime.h>

// relationalGraphStack — round 2
// Changes vs R1:
//  - Both GEMMs now use v_mfma_f32_16x16x32_bf16 (bf16 in, f32 accum), no LDS.
//  - x converted to bf16 once; weights packed to bf16 once; h stored bf16 only.
//  - xb/hb scratch live in d_out's upper half (dead before gather2 rewrites it).
//  - s2 aliases h_pre region (sequentially dead); part buffer shared.

#define GATHER_GRID 2048
#define SCAN_CHUNK 4096

typedef short bf16x8 __attribute__((ext_vector_type(8)));
typedef float f32x4 __attribute__((ext_vector_type(4)));

static __device__ __forceinline__ float bf2f(unsigned short u) {
  return __uint_as_float(((unsigned)u) << 16);
}
static __device__ __forceinline__ unsigned short f2bf(float f) {
  unsigned u = __float_as_uint(f);
  u += 0x7FFFu + ((u >> 16) & 1u);  // round to nearest even
  return (unsigned short)(u >> 16);
}

__global__ void k_zero(float* __restrict__ deg, int* __restrict__ cnt, int n) {
  int i = blockIdx.x * blockDim.x + threadIdx.x;
  int stride = gridDim.x * blockDim.x;
  for (int k = i; k < n; k += stride) { deg[k] = 0.f; cnt[k] = 0; }
}

__global__ void k_count(const float* __restrict__ w, const int* __restrict__ node_out,
                        const int* __restrict__ rel, float* __restrict__ deg,
                        int* __restrict__ cnt, int E, int R) {
  int i = blockIdx.x * blockDim.x + threadIdx.x;
  int stride = gridDim.x * blockDim.x;
  for (int e = i; e < E; e += stride) {
    int seg = node_out[e] * R + rel[e];
    atomicAdd(&deg[seg], w[e]);
    atomicAdd(&cnt[seg], 1);
  }
}

__global__ __launch_bounds__(256) void k_scan1(const int* __restrict__ cnt,
                                               int* __restrict__ bsum, int NR) {
  __shared__ int red[256];
  int tid = threadIdx.x;
  int base = blockIdx.x * SCAN_CHUNK;
  int s = 0;
  for (int i = tid; i < SCAN_CHUNK; i += 256) {
    int idx = base + i;
    if (idx < NR) s += cnt[idx];
  }
  red[tid] = s;
  __syncthreads();
  for (int off = 128; off > 0; off >>= 1) {
    if (tid < off) red[tid] += red[tid + off];
    __syncthreads();
  }
  if (tid == 0) bsum[blockIdx.x] = red[0];
}

__global__ void k_scan2(const int* __restrict__ bsum, int* __restrict__ bpre,
                        int* __restrict__ rowptr_end, int NB) {
  int lane = threadIdx.x;
  int carry = 0;
  for (int base = 0; base < NB; base += 64) {
    int i = base + lane;
    int v = (i < NB) ? bsum[i] : 0;
    int incl = v;
    #pragma unroll
    for (int off = 1; off < 64; off <<= 1) {
      int u = __shfl_up(incl, off);
      if (lane >= off) incl += u;
    }
    if (i < NB) bpre[i] = carry + incl - v;
    carry += __shfl(incl, 63);
  }
  if (lane == 0) *rowptr_end = carry;
}

__global__ __launch_bounds__(256) void k_scan3(const int* __restrict__ cnt,
                                               const int* __restrict__ bpre,
                                               int* __restrict__ rowptr,
                                               int* __restrict__ wptr, int NR) {
  __shared__ int wtot[4];
  int tid = threadIdx.x, lane = tid & 63, wid = tid >> 6;
  int base = blockIdx.x * SCAN_CHUNK + tid * 16;
  int v[16];
  int t = 0;
  #pragma unroll
  for (int i = 0; i < 16; i++) {
    int idx = base + i;
    v[i] = (idx < NR) ? cnt[idx] : 0;
    t += v[i];
  }
  int incl = t;
  #pragma unroll
  for (int off = 1; off < 64; off <<= 1) {
    int u = __shfl_up(incl, off);
    if (lane >= off) incl += u;
  }
  if (lane == 63) wtot[wid] = incl;
  __syncthreads();
  int woff = 0;
  for (int w = 0; w < wid; w++) woff += wtot[w];
  int start = bpre[blockIdx.x] + woff + incl - t;
  #pragma unroll
  for (int i = 0; i < 16; i++) {
    int idx = base + i;
    if (idx < NR) { rowptr[idx] = start; wptr[idx] = start; }
    start += v[i];
  }
}

__global__ void k_fill(const float* __restrict__ w, const int* __restrict__ node_out,
                       const int* __restrict__ node_in, const int* __restrict__ rel,
                       const float* __restrict__ deg, int* __restrict__ wptr,
                       int2* __restrict__ ep, int E, int R) {
  int i = blockIdx.x * blockDim.x + threadIdx.x;
  int stride = gridDim.x * blockDim.x;
  for (int e = i; e < E; e += stride) {
    int seg = node_out[e] * R + rel[e];
    int pos = atomicAdd(&wptr[seg], 1);
    float v = w[e] / deg[seg];
    ep[pos] = make_int2(node_in[e], __float_as_int(v));
  }
}

// f32 -> bf16 convert (x)
__global__ void k_f2b(const float4* __restrict__ in, ushort4* __restrict__ out, int n4) {
  int i = blockIdx.x * blockDim.x + threadIdx.x;
  int stride = gridDim.x * blockDim.x;
  for (int k = i; k < n4; k += stride) {
    float4 v = in[k];
    ushort4 o;
    o.x = f2bf(v.x); o.y = f2bf(v.y); o.z = f2bf(v.z); o.w = f2bf(v.w);
    out[k] = o;
  }
}

// pack all weights to bf16:
//  wb1: 576 rows x 64: rows [0,512): wb1[(s*64+j)*64+d] = W_lin1[j*512 + s*64 + d]
//       rows [512,576): W_self1[j*64+d]
//  wb2: 128 rows x 64: rows [0,64) W_lin2, rows [64,128) W_self2
__global__ void k_packW(const float* __restrict__ Wlin1, const float* __restrict__ Wself1,
                        const float* __restrict__ Wlin2, const float* __restrict__ Wself2,
                        unsigned short* __restrict__ wb1, unsigned short* __restrict__ wb2,
                        int R) {
  int i = blockIdx.x * blockDim.x + threadIdx.x;
  int stride = gridDim.x * blockDim.x;
  int n1 = (R + 1) * 64 * 64;   // 576*64
  int n2 = 2 * 64 * 64;         // 128*64
  for (int k = i; k < n1 + n2; k += stride) {
    if (k < n1) {
      int r = k >> 6, d = k & 63;
      float v;
      if (r < R * 64) {
        int s = r >> 6, j = r & 63;
        v = Wlin1[j * (R * 64) + s * 64 + d];
      } else {
        v = Wself1[(r - R * 64) * 64 + d];
      }
      wb1[k] = f2bf(v);
    } else {
      int k2 = k - n1;
      int r = k2 >> 6, d = k2 & 63;
      float v = (r < 64) ? Wlin2[r * 64 + d] : Wself2[(r - 64) * 64 + d];
      wb2[k2] = f2bf(v);
    }
  }
}

// MFMA GEMM: out[slab][m][j] = sum_d A[m][d] * Wb[slab*64+j][d], K=64.
// slabs [0,nslab) -> bf16 outLinB[slab*M*64 + ...]; slab==nslab -> f32 outSelf.
// block = 256 thr (4 waves), each block does 64 rows x all slabs.
__global__ __launch_bounds__(256) void k_gemm_mfma(
    const unsigned short* __restrict__ A, int M,
    const unsigned short* __restrict__ Wb, int nslab,
    unsigned short* __restrict__ outLinB, float* __restrict__ outSelf) {
  int m0 = blockIdx.x * 64;
  int wid = threadIdx.x >> 6;
  int lane = threadIdx.x & 63;
  int mrow = m0 + wid * 16 + (lane & 15);
  int mload = (mrow < M) ? mrow : (M - 1);
  const unsigned short* arow = A + (size_t)mload * 64 + 8 * (lane >> 4);
  bf16x8 a0 = *(const bf16x8*)(arow);
  bf16x8 a1 = *(const bf16x8*)(arow + 32);
  int rbase = m0 + wid * 16 + ((lane >> 4) << 2);
  int cbase = lane & 15;
  for (int slab = 0; slab <= nslab; ++slab) {
    const unsigned short* wrow = Wb + ((size_t)slab * 64 + (lane & 15)) * 64 + 8 * (lane >> 4);
    f32x4 acc[4];
    #pragma unroll
    for (int nt = 0; nt < 4; ++nt) {
      bf16x8 b0 = *(const bf16x8*)(wrow + nt * 16 * 64);
      bf16x8 b1 = *(const bf16x8*)(wrow + nt * 16 * 64 + 32);
      f32x4 c = {};
      c = __builtin_amdgcn_mfma_f32_16x16x32_bf16(a0, b0, c, 0, 0, 0);
      c = __builtin_amdgcn_mfma_f32_16x16x32_bf16(a1, b1, c, 0, 0, 0);
      acc[nt] = c;
    }
    if (slab < nslab) {
      unsigned short* op = outLinB + (size_t)slab * M * 64;
      #pragma unroll
      for (int nt = 0; nt < 4; ++nt) {
        int col = nt * 16 + cbase;
        #pragma unroll
        for (int rg = 0; rg < 4; ++rg) {
          int grow = rbase + rg;
          if (grow < M) op[(size_t)grow * 64 + col] = f2bf(acc[nt][rg]);
        }
      }
    } else {
      #pragma unroll
      for (int nt = 0; nt < 4; ++nt) {
        int col = nt * 16 + cbase;
        #pragma unroll
        for (int rg = 0; rg < 4; ++rg) {
          int grow = rbase + rg;
          if (grow < M) outSelf[(size_t)grow * 64 + col] = acc[nt][rg];
        }
      }
    }
  }
}

// layer1: h_pre[n,j] = s1[n,j] + sum_r sum_{e in seg(n,r)} w_e * y1[r, src_e, j]
__global__ __launch_bounds__(256) void k_gather1(
    const int* __restrict__ rowptr, const int2* __restrict__ ep,
    const unsigned short* __restrict__ y1, const float* __restrict__ s1,
    float* __restrict__ h, float* __restrict__ part, int N, int R) {
  int lane = threadIdx.x & 63;
  int wid = threadIdx.x >> 6;
  int gw = blockIdx.x * 4 + wid;
  int nw = gridDim.x * 4;
  float lsum = 0.f, lsq = 0.f;
  for (int n = gw; n < N; n += nw) {
    float acc = s1[(size_t)n * 64 + lane];
    int segbase = n * R;
    int k = rowptr[segbase];
    for (int r = 0; r < R; r++) {
      int kend = rowptr[segbase + r + 1];
      const unsigned short* yb = y1 + (size_t)r * N * 64;
      while (k < kend) {
        int cnt = kend - k; if (cnt > 64) cnt = 64;
        int2 v = (lane < cnt) ? ep[k + lane] : make_int2(0, 0);
        for (int tt = 0; tt < cnt; tt++) {
          int src = __shfl(v.x, tt);
          float wgt = __int_as_float(__shfl(v.y, tt));
          acc += wgt * bf2f(yb[(size_t)src * 64 + lane]);
        }
        k = (cnt == 64) ? k + 64 : kend;
      }
    }
    h[(size_t)n * 64 + lane] = acc;
    lsum += acc; lsq += acc * acc;
  }
  __shared__ float sp[4][64], sq2[4][64];
  sp[wid][lane] = lsum; sq2[wid][lane] = lsq;
  __syncthreads();
  if (threadIdx.x < 64) {
    float s = 0.f, q = 0.f;
    for (int w2 = 0; w2 < 4; w2++) { s += sp[w2][threadIdx.x]; q += sq2[w2][threadIdx.x]; }
    part[(size_t)blockIdx.x * 128 + threadIdx.x] = s;
    part[(size_t)blockIdx.x * 128 + 64 + threadIdx.x] = q;
  }
}

// layer2: out[r*N+n, j] = s2[n,j] + sum_{e in seg(n,r)} w_e * z[src_e, j]
__global__ __launch_bounds__(256) void k_gather2(
    const int* __restrict__ rowptr, const int2* __restrict__ ep,
    const unsigned short* __restrict__ z, const float* __restrict__ s2,
    float* __restrict__ out, float* __restrict__ part, int N, int R) {
  int lane = threadIdx.x & 63;
  int wid = threadIdx.x >> 6;
  int gw = blockIdx.x * 4 + wid;
  int nw = gridDim.x * 4;
  float lsum = 0.f, lsq = 0.f;
  for (int n = gw; n < N; n += nw) {
    float sv = s2[(size_t)n * 64 + lane];
    int segbase = n * R;
    int k = rowptr[segbase];
    for (int r = 0; r < R; r++) {
      int kend = rowptr[segbase + r + 1];
      float acc = 0.f;
      while (k < kend) {
        int cnt = kend - k; if (cnt > 64) cnt = 64;
        int2 v = (lane < cnt) ? ep[k + lane] : make_int2(0, 0);
        for (int tt = 0; tt < cnt; tt++) {
          int src = __shfl(v.x, tt);
          float wgt = __int_as_float(__shfl(v.y, tt));
          acc += wgt * bf2f(z[(size_t)src * 64 + lane]);
        }
        k = (cnt == 64) ? k + 64 : kend;
      }
      float val = acc + sv;
      out[((size_t)r * N + n) * 64 + lane] = val;
      lsum += val; lsq += val * val;
    }
  }
  __shared__ float sp[4][64], sq2[4][64];
  sp[wid][lane] = lsum; sq2[wid][lane] = lsq;
  __syncthreads();
  if (threadIdx.x < 64) {
    float s = 0.f, q = 0.f;
    for (int w2 = 0; w2 < 4; w2++) { s += sp[w2][threadIdx.x]; q += sq2[w2][threadIdx.x]; }
    part[(size_t)blockIdx.x * 128 + threadIdx.x] = s;
    part[(size_t)blockIdx.x * 128 + 64 + threadIdx.x] = q;
  }
}

__global__ __launch_bounds__(1024) void k_bnstats(
    const float* __restrict__ part, int P, float M,
    const float* __restrict__ gamma, const float* __restrict__ beta,
    float* __restrict__ ss) {
  __shared__ float red[1024];
  int tid = threadIdx.x;
  int j = tid & 127;
  int g = tid >> 7;
  float acc = 0.f;
  for (int i = g; i < P; i += 8) acc += part[(size_t)i * 128 + j];
  red[tid] = acc;
  __syncthreads();
  if (tid < 128) {
    float s = 0.f;
    for (int gg = 0; gg < 8; gg++) s += red[gg * 128 + tid];
    red[tid] = s;
  }
  __syncthreads();
  if (tid < 64) {
    float s = red[tid], q = red[64 + tid];
    float mean = s / M;
    float var = q / M - mean * mean;
    float sc = gamma[tid] / sqrtf(var + 1e-5f);
    ss[tid] = sc;
    ss[64 + tid] = beta[tid] - mean * sc;
  }
}

// bn+relu, f32 in-place (final output)
__global__ void k_bnrelu4(float4* __restrict__ buf, const float* __restrict__ ss, long total4) {
  __shared__ float s_ss[128];
  if (threadIdx.x < 128) s_ss[threadIdx.x] = ss[threadIdx.x];
  __syncthreads();
  long i = (long)blockIdx.x * blockDim.x + threadIdx.x;
  long stride = (long)gridDim.x * blockDim.x;
  for (long k = i; k < total4; k += stride) {
    float4 v = buf[k];
    int j0 = ((int)k & 15) * 4;
    v.x = fmaxf(fmaf(v.x, s_ss[j0 + 0], s_ss[64 + j0 + 0]), 0.f);
    v.y = fmaxf(fmaf(v.y, s_ss[j0 + 1], s_ss[64 + j0 + 1]), 0.f);
    v.z = fmaxf(fmaf(v.z, s_ss[j0 + 2], s_ss[64 + j0 + 2]), 0.f);
    v.w = fmaxf(fmaf(v.w, s_ss[j0 + 3], s_ss[64 + j0 + 3]), 0.f);
    buf[k] = v;
  }
}

// bn+relu, f32 in -> bf16 out (h)
__global__ void k_bnrelu_f2b(const float4* __restrict__ in, ushort4* __restrict__ out,
                             const float* __restrict__ ss, long total4) {
  __shared__ float s_ss[128];
  if (threadIdx.x < 128) s_ss[threadIdx.x] = ss[threadIdx.x];
  __syncthreads();
  long i = (long)blockIdx.x * blockDim.x + threadIdx.x;
  long stride = (long)gridDim.x * blockDim.x;
  for (long k = i; k < total4; k += stride) {
    float4 v = in[k];
    int j0 = ((int)k & 15) * 4;
    ushort4 o;
    o.x = f2bf(fmaxf(fmaf(v.x, s_ss[j0 + 0], s_ss[64 + j0 + 0]), 0.f));
    o.y = f2bf(fmaxf(fmaf(v.y, s_ss[j0 + 1], s_ss[64 + j0 + 1]), 0.f));
    o.z = f2bf(fmaxf(fmaf(v.z, s_ss[j0 + 2], s_ss[64 + j0 + 2]), 0.f));
    o.w = f2bf(fmaxf(fmaf(v.w, s_ss[j0 + 3], s_ss[64 + j0 + 3]), 0.f));
    out[k] = o;
  }
}

extern "C" void kernel_launch(void* const* d_in, const int* in_sizes, int n_in,
                              void* d_out, int out_size, void* d_ws, size_t ws_size,
                              hipStream_t stream) {
  const float* x        = (const float*)d_in[0];
  const float* edge_w   = (const float*)d_in[1];
  const float* W_lin1   = (const float*)d_in[2];
  const float* W_self1  = (const float*)d_in[4];
  const float* gamma1   = (const float*)d_in[6];
  const float* beta1    = (const float*)d_in[7];
  const float* W_lin2   = (const float*)d_in[8];
  const float* W_self2  = (const float*)d_in[10];
  const float* gamma2   = (const float*)d_in[12];
  const float* beta2    = (const float*)d_in[13];
  const int* node_in    = (const int*)d_in[14];
  const int* node_out   = (const int*)d_in[15];
  const int* relation   = (const int*)d_in[16];

  int N = in_sizes[0] / 64;           // 50000
  int E = in_sizes[1];                // 800000
  int R = in_sizes[2] / (64 * 64);    // 8
  int NR = N * R;                     // 400000
  int NB = (NR + SCAN_CHUNK - 1) / SCAN_CHUNK;

  char* p = (char*)d_ws;
  auto alloc = [&](size_t bytes) { char* r = p; p += (bytes + 255) & ~(size_t)255; return r; };
  float* deg    = (float*)alloc(4ull * NR);
  int* cnt      = (int*)alloc(4ull * NR);
  int* rowptr   = (int*)alloc(4ull * (NR + 1));
  int* wptr     = (int*)alloc(4ull * NR);
  int* bsum     = (int*)alloc(4ull * NB);
  int* bpre     = (int*)alloc(4ull * NB);
  int2* ep      = (int2*)alloc(8ull * E);
  unsigned short* wb1 = (unsigned short*)alloc(2ull * (R + 1) * 64 * 64);
  unsigned short* wb2 = (unsigned short*)alloc(2ull * 2 * 64 * 64);
  float* s1     = (float*)alloc(4ull * N * 64);
  float* h_pre  = (float*)alloc(4ull * N * 64);   // aliased by s2 after bnrelu1
  unsigned short* z = (unsigned short*)alloc(2ull * N * 64);
  float* part   = (float*)alloc(4ull * GATHER_GRID * 128);
  float* ss1    = (float*)alloc(4ull * 128);
  float* ss2    = (float*)alloc(4ull * 128);
  float* s2     = h_pre;  // alias: h_pre dead after k_bnrelu_f2b, s2 written by gemm2 after

  // d_out upper half as scratch: y1 bf16 occupies [0, R*N*64*2); xb, hb after it.
  unsigned short* y1 = (unsigned short*)d_out;                     // 51.2MB
  unsigned short* xb = (unsigned short*)((char*)d_out + 2ull * R * N * 64);  // 6.4MB
  unsigned short* hb = xb + (size_t)N * 64;                        // 6.4MB

  k_zero<<<512, 256, 0, stream>>>(deg, cnt, NR);
  k_count<<<1024, 256, 0, stream>>>(edge_w, node_out, relation, deg, cnt, E, R);
  k_scan1<<<NB, 256, 0, stream>>>(cnt, bsum, NR);
  k_scan2<<<1, 64, 0, stream>>>(bsum, bpre, &rowptr[NR], NB);
  k_scan3<<<NB, 256, 0, stream>>>(cnt, bpre, rowptr, wptr, NR);
  k_fill<<<1024, 256, 0, stream>>>(edge_w, node_out, node_in, relation, deg, wptr, ep, E, R);

  k_f2b<<<1024, 256, 0, stream>>>((const float4*)x, (ushort4*)xb, N * 64 / 4);
  k_packW<<<64, 256, 0, stream>>>(W_lin1, W_self1, W_lin2, W_self2, wb1, wb2, R);

  // layer 1: y1[r] = x @ W_r^T (bf16 out), s1 = x @ W_self1^T (f32 out)
  int mblocks = (N + 63) / 64;
  k_gemm_mfma<<<mblocks, 256, 0, stream>>>(xb, N, wb1, R, y1, s1);
  k_gather1<<<GATHER_GRID, 256, 0, stream>>>(rowptr, ep, y1, s1, h_pre, part, N, R);
  k_bnstats<<<1, 1024, 0, stream>>>(part, GATHER_GRID, (float)N, gamma1, beta1, ss1);
  k_bnrelu_f2b<<<2048, 256, 0, stream>>>((const float4*)h_pre, (ushort4*)hb, ss1, (long)N * 64 / 4);

  // layer 2: z = h @ W_lin2^T (bf16), s2 = h @ W_self2^T (f32)
  k_gemm_mfma<<<mblocks, 256, 0, stream>>>(hb, N, wb2, 1, z, s2);
  k_gather2<<<GATHER_GRID, 256, 0, stream>>>(rowptr, ep, z, s2, (float*)d_out, part, N, R);
  k_bnstats<<<1, 1024, 0, stream>>>(part, GATHER_GRID, (float)N * R, gamma2, beta2, ss2);
  k_bnrelu4<<<4096, 256, 0, stream>>>((float4*)d_out, ss2, (long)N * R * 64 / 4);
}

// Round 4
// 455.029 us; speedup vs baseline: 1.4070x; 1.1747x over previous
//
#include <hip/hip_runtime.h>

// relationalGraphStack — round 3
// Changes vs R2:
//  - Both gathers restructured: 16 lanes per edge-row (ushort4 cols), 4 edges
//    per wave-instruction, lane-local loads (no shuffle-broadcast serial chain).
//  - Edge payload packs (src | rel<<16, w): gather1 walks a flat per-node edge
//    range (no segment loop); gather2 flushes per segment (avg 2 edges -> 1 iter).
//  - h_pre stored bf16 (stats still computed from exact f32).

#define GATHER_GRID 2048
#define SCAN_CHUNK 4096

typedef short bf16x8 __attribute__((ext_vector_type(8)));
typedef float f32x4 __attribute__((ext_vector_type(4)));

static __device__ __forceinline__ float bf2f(unsigned short u) {
  return __uint_as_float(((unsigned)u) << 16);
}
static __device__ __forceinline__ unsigned short f2bf(float f) {
  unsigned u = __float_as_uint(f);
  u += 0x7FFFu + ((u >> 16) & 1u);  // round to nearest even
  return (unsigned short)(u >> 16);
}

__global__ void k_zero(float* __restrict__ deg, int* __restrict__ cnt, int n) {
  int i = blockIdx.x * blockDim.x + threadIdx.x;
  int stride = gridDim.x * blockDim.x;
  for (int k = i; k < n; k += stride) { deg[k] = 0.f; cnt[k] = 0; }
}

__global__ void k_count(const float* __restrict__ w, const int* __restrict__ node_out,
                        const int* __restrict__ rel, float* __restrict__ deg,
                        int* __restrict__ cnt, int E, int R) {
  int i = blockIdx.x * blockDim.x + threadIdx.x;
  int stride = gridDim.x * blockDim.x;
  for (int e = i; e < E; e += stride) {
    int seg = node_out[e] * R + rel[e];
    atomicAdd(&deg[seg], w[e]);
    atomicAdd(&cnt[seg], 1);
  }
}

__global__ __launch_bounds__(256) void k_scan1(const int* __restrict__ cnt,
                                               int* __restrict__ bsum, int NR) {
  __shared__ int red[256];
  int tid = threadIdx.x;
  int base = blockIdx.x * SCAN_CHUNK;
  int s = 0;
  for (int i = tid; i < SCAN_CHUNK; i += 256) {
    int idx = base + i;
    if (idx < NR) s += cnt[idx];
  }
  red[tid] = s;
  __syncthreads();
  for (int off = 128; off > 0; off >>= 1) {
    if (tid < off) red[tid] += red[tid + off];
    __syncthreads();
  }
  if (tid == 0) bsum[blockIdx.x] = red[0];
}

__global__ void k_scan2(const int* __restrict__ bsum, int* __restrict__ bpre,
                        int* __restrict__ rowptr_end, int NB) {
  int lane = threadIdx.x;
  int carry = 0;
  for (int base = 0; base < NB; base += 64) {
    int i = base + lane;
    int v = (i < NB) ? bsum[i] : 0;
    int incl = v;
    #pragma unroll
    for (int off = 1; off < 64; off <<= 1) {
      int u = __shfl_up(incl, off);
      if (lane >= off) incl += u;
    }
    if (i < NB) bpre[i] = carry + incl - v;
    carry += __shfl(incl, 63);
  }
  if (lane == 0) *rowptr_end = carry;
}

__global__ __launch_bounds__(256) void k_scan3(const int* __restrict__ cnt,
                                               const int* __restrict__ bpre,
                                               int* __restrict__ rowptr,
                                               int* __restrict__ wptr, int NR) {
  __shared__ int wtot[4];
  int tid = threadIdx.x, lane = tid & 63, wid = tid >> 6;
  int base = blockIdx.x * SCAN_CHUNK + tid * 16;
  int v[16];
  int t = 0;
  #pragma unroll
  for (int i = 0; i < 16; i++) {
    int idx = base + i;
    v[i] = (idx < NR) ? cnt[idx] : 0;
    t += v[i];
  }
  int incl = t;
  #pragma unroll
  for (int off = 1; off < 64; off <<= 1) {
    int u = __shfl_up(incl, off);
    if (lane >= off) incl += u;
  }
  if (lane == 63) wtot[wid] = incl;
  __syncthreads();
  int woff = 0;
  for (int w = 0; w < wid; w++) woff += wtot[w];
  int start = bpre[blockIdx.x] + woff + incl - t;
  #pragma unroll
  for (int i = 0; i < 16; i++) {
    int idx = base + i;
    if (idx < NR) { rowptr[idx] = start; wptr[idx] = start; }
    start += v[i];
  }
}

// payload: ep[pos] = (src | rel<<16, w/deg as float bits)   [requires N <= 65536]
__global__ void k_fill(const float* __restrict__ w, const int* __restrict__ node_out,
                       const int* __restrict__ node_in, const int* __restrict__ rel,
                       const float* __restrict__ deg, int* __restrict__ wptr,
                       int2* __restrict__ ep, int E, int R) {
  int i = blockIdx.x * blockDim.x + threadIdx.x;
  int stride = gridDim.x * blockDim.x;
  for (int e = i; e < E; e += stride) {
    int rr = rel[e];
    int seg = node_out[e] * R + rr;
    int pos = atomicAdd(&wptr[seg], 1);
    float v = w[e] / deg[seg];
    ep[pos] = make_int2(node_in[e] | (rr << 16), __float_as_int(v));
  }
}

// f32 -> bf16 convert (x)
__global__ void k_f2b(const float4* __restrict__ in, ushort4* __restrict__ out, int n4) {
  int i = blockIdx.x * blockDim.x + threadIdx.x;
  int stride = gridDim.x * blockDim.x;
  for (int k = i; k < n4; k += stride) {
    float4 v = in[k];
    ushort4 o;
    o.x = f2bf(v.x); o.y = f2bf(v.y); o.z = f2bf(v.z); o.w = f2bf(v.w);
    out[k] = o;
  }
}

__global__ void k_packW(const float* __restrict__ Wlin1, const float* __restrict__ Wself1,
                        const float* __restrict__ Wlin2, const float* __restrict__ Wself2,
                        unsigned short* __restrict__ wb1, unsigned short* __restrict__ wb2,
                        int R) {
  int i = blockIdx.x * blockDim.x + threadIdx.x;
  int stride = gridDim.x * blockDim.x;
  int n1 = (R + 1) * 64 * 64;
  int n2 = 2 * 64 * 64;
  for (int k = i; k < n1 + n2; k += stride) {
    if (k < n1) {
      int r = k >> 6, d = k & 63;
      float v;
      if (r < R * 64) {
        int s = r >> 6, j = r & 63;
        v = Wlin1[j * (R * 64) + s * 64 + d];
      } else {
        v = Wself1[(r - R * 64) * 64 + d];
      }
      wb1[k] = f2bf(v);
    } else {
      int k2 = k - n1;
      int r = k2 >> 6, d = k2 & 63;
      float v = (r < 64) ? Wlin2[r * 64 + d] : Wself2[(r - 64) * 64 + d];
      wb2[k2] = f2bf(v);
    }
  }
}

// MFMA GEMM (unchanged from R2)
__global__ __launch_bounds__(256) void k_gemm_mfma(
    const unsigned short* __restrict__ A, int M,
    const unsigned short* __restrict__ Wb, int nslab,
    unsigned short* __restrict__ outLinB, float* __restrict__ outSelf) {
  int m0 = blockIdx.x * 64;
  int wid = threadIdx.x >> 6;
  int lane = threadIdx.x & 63;
  int mrow = m0 + wid * 16 + (lane & 15);
  int mload = (mrow < M) ? mrow : (M - 1);
  const unsigned short* arow = A + (size_t)mload * 64 + 8 * (lane >> 4);
  bf16x8 a0 = *(const bf16x8*)(arow);
  bf16x8 a1 = *(const bf16x8*)(arow + 32);
  int rbase = m0 + wid * 16 + ((lane >> 4) << 2);
  int cbase = lane & 15;
  for (int slab = 0; slab <= nslab; ++slab) {
    const unsigned short* wrow = Wb + ((size_t)slab * 64 + (lane & 15)) * 64 + 8 * (lane >> 4);
    f32x4 acc[4];
    #pragma unroll
    for (int nt = 0; nt < 4; ++nt) {
      bf16x8 b0 = *(const bf16x8*)(wrow + nt * 16 * 64);
      bf16x8 b1 = *(const bf16x8*)(wrow + nt * 16 * 64 + 32);
      f32x4 c = {};
      c = __builtin_amdgcn_mfma_f32_16x16x32_bf16(a0, b0, c, 0, 0, 0);
      c = __builtin_amdgcn_mfma_f32_16x16x32_bf16(a1, b1, c, 0, 0, 0);
      acc[nt] = c;
    }
    if (slab < nslab) {
      unsigned short* op = outLinB + (size_t)slab * M * 64;
      #pragma unroll
      for (int nt = 0; nt < 4; ++nt) {
        int col = nt * 16 + cbase;
        #pragma unroll
        for (int rg = 0; rg < 4; ++rg) {
          int grow = rbase + rg;
          if (grow < M) op[(size_t)grow * 64 + col] = f2bf(acc[nt][rg]);
        }
      }
    } else {
      #pragma unroll
      for (int nt = 0; nt < 4; ++nt) {
        int col = nt * 16 + cbase;
        #pragma unroll
        for (int rg = 0; rg < 4; ++rg) {
          int grow = rbase + rg;
          if (grow < M) outSelf[(size_t)grow * 64 + col] = acc[nt][rg];
        }
      }
    }
  }
}

// layer1 gather, MLP-friendly: 16 lanes per row, 4 edges in flight, flat edge range.
// h_pre[n,c] = s1[n,c] + sum_{e in edges(n)} w_e * y1[rel_e*N + src_e, c]  (bf16 out)
__global__ __launch_bounds__(256) void k_gather1(
    const int* __restrict__ rowptr, const int2* __restrict__ ep,
    const unsigned short* __restrict__ y1, const float* __restrict__ s1,
    unsigned short* __restrict__ h_pre, float* __restrict__ part, int N, int R) {
  int lane = threadIdx.x & 63;
  int wid = threadIdx.x >> 6;
  int l16 = lane & 15;        // col block
  int lg = lane >> 4;         // edge slot
  int c0 = l16 * 4;
  int gw = blockIdx.x * 4 + wid;
  int nw = gridDim.x * 4;
  float lsum[4] = {0.f, 0.f, 0.f, 0.f}, lsq[4] = {0.f, 0.f, 0.f, 0.f};
  for (int n = gw; n < N; n += nw) {
    int k0 = rowptr[n * R];
    int kend = rowptr[n * R + R];
    float a0 = 0.f, a1 = 0.f, a2 = 0.f, a3 = 0.f;
    #pragma unroll 2
    for (int k = k0 + lg; k < kend; k += 4) {
      int2 p = ep[k];
      int src = p.x & 0xFFFF;
      int rr = p.x >> 16;
      float w = __int_as_float(p.y);
      ushort4 u = *(const ushort4*)&y1[((size_t)(rr * N + src)) * 64 + c0];
      a0 = fmaf(w, bf2f(u.x), a0);
      a1 = fmaf(w, bf2f(u.y), a1);
      a2 = fmaf(w, bf2f(u.z), a2);
      a3 = fmaf(w, bf2f(u.w), a3);
    }
    a0 += __shfl_xor(a0, 16); a0 += __shfl_xor(a0, 32);
    a1 += __shfl_xor(a1, 16); a1 += __shfl_xor(a1, 32);
    a2 += __shfl_xor(a2, 16); a2 += __shfl_xor(a2, 32);
    a3 += __shfl_xor(a3, 16); a3 += __shfl_xor(a3, 32);
    if (lg == 0) {
      float4 s = *(const float4*)&s1[(size_t)n * 64 + c0];
      float v0 = a0 + s.x, v1 = a1 + s.y, v2 = a2 + s.z, v3 = a3 + s.w;
      ushort4 o; o.x = f2bf(v0); o.y = f2bf(v1); o.z = f2bf(v2); o.w = f2bf(v3);
      *(ushort4*)&h_pre[(size_t)n * 64 + c0] = o;
      lsum[0] += v0; lsq[0] += v0 * v0;
      lsum[1] += v1; lsq[1] += v1 * v1;
      lsum[2] += v2; lsq[2] += v2 * v2;
      lsum[3] += v3; lsq[3] += v3 * v3;
    }
  }
  __shared__ float sp[4][16][4], sq[4][16][4];
  if (lg == 0) {
    #pragma unroll
    for (int i = 0; i < 4; i++) { sp[wid][l16][i] = lsum[i]; sq[wid][l16][i] = lsq[i]; }
  }
  __syncthreads();
  if (threadIdx.x < 64) {
    int j = threadIdx.x;
    float s = 0.f, q = 0.f;
    for (int w2 = 0; w2 < 4; w2++) { s += sp[w2][j >> 2][j & 3]; q += sq[w2][j >> 2][j & 3]; }
    part[(size_t)blockIdx.x * 128 + j] = s;
    part[(size_t)blockIdx.x * 128 + 64 + j] = q;
  }
}

// layer2 gather: per-segment flush; 16 lanes per row, 4 edges in flight.
// out[(r*N+n),c] = s2[n,c] + sum_{e in seg(n,r)} w_e * z[src_e, c]   (f32 out)
__global__ __launch_bounds__(256) void k_gather2(
    const int* __restrict__ rowptr, const int2* __restrict__ ep,
    const unsigned short* __restrict__ z, const float* __restrict__ s2,
    float* __restrict__ out, float* __restrict__ part, int N, int R) {
  int lane = threadIdx.x & 63;
  int wid = threadIdx.x >> 6;
  int l16 = lane & 15;
  int lg = lane >> 4;
  int c0 = l16 * 4;
  int gw = blockIdx.x * 4 + wid;
  int nw = gridDim.x * 4;
  float lsum[4] = {0.f, 0.f, 0.f, 0.f}, lsq[4] = {0.f, 0.f, 0.f, 0.f};
  for (int n = gw; n < N; n += nw) {
    float4 sv = *(const float4*)&s2[(size_t)n * 64 + c0];
    int segbase = n * R;
    int k1 = rowptr[segbase];
    for (int r = 0; r < R; r++) {
      int k0 = k1;
      k1 = rowptr[segbase + r + 1];
      float a0 = 0.f, a1 = 0.f, a2 = 0.f, a3 = 0.f;
      #pragma unroll 2
      for (int k = k0 + lg; k < k1; k += 4) {
        int2 p = ep[k];
        int src = p.x & 0xFFFF;
        float w = __int_as_float(p.y);
        ushort4 u = *(const ushort4*)&z[(size_t)src * 64 + c0];
        a0 = fmaf(w, bf2f(u.x), a0);
        a1 = fmaf(w, bf2f(u.y), a1);
        a2 = fmaf(w, bf2f(u.z), a2);
        a3 = fmaf(w, bf2f(u.w), a3);
      }
      a0 += __shfl_xor(a0, 16); a0 += __shfl_xor(a0, 32);
      a1 += __shfl_xor(a1, 16); a1 += __shfl_xor(a1, 32);
      a2 += __shfl_xor(a2, 16); a2 += __shfl_xor(a2, 32);
      a3 += __shfl_xor(a3, 16); a3 += __shfl_xor(a3, 32);
      if (lg == 0) {
        float v0 = a0 + sv.x, v1 = a1 + sv.y, v2 = a2 + sv.z, v3 = a3 + sv.w;
        *(float4*)&out[((size_t)r * N + n) * 64 + c0] = make_float4(v0, v1, v2, v3);
        lsum[0] += v0; lsq[0] += v0 * v0;
        lsum[1] += v1; lsq[1] += v1 * v1;
        lsum[2] += v2; lsq[2] += v2 * v2;
        lsum[3] += v3; lsq[3] += v3 * v3;
      }
    }
  }
  __shared__ float sp[4][16][4], sq[4][16][4];
  if (lg == 0) {
    #pragma unroll
    for (int i = 0; i < 4; i++) { sp[wid][l16][i] = lsum[i]; sq[wid][l16][i] = lsq[i]; }
  }
  __syncthreads();
  if (threadIdx.x < 64) {
    int j = threadIdx.x;
    float s = 0.f, q = 0.f;
    for (int w2 = 0; w2 < 4; w2++) { s += sp[w2][j >> 2][j & 3]; q += sq[w2][j >> 2][j & 3]; }
    part[(size_t)blockIdx.x * 128 + j] = s;
    part[(size_t)blockIdx.x * 128 + 64 + j] = q;
  }
}

__global__ __launch_bounds__(1024) void k_bnstats(
    const float* __restrict__ part, int P, float M,
    const float* __restrict__ gamma, const float* __restrict__ beta,
    float* __restrict__ ss) {
  __shared__ float red[1024];
  int tid = threadIdx.x;
  int j = tid & 127;
  int g = tid >> 7;
  float acc = 0.f;
  for (int i = g; i < P; i += 8) acc += part[(size_t)i * 128 + j];
  red[tid] = acc;
  __syncthreads();
  if (tid < 128) {
    float s = 0.f;
    for (int gg = 0; gg < 8; gg++) s += red[gg * 128 + tid];
    red[tid] = s;
  }
  __syncthreads();
  if (tid < 64) {
    float s = red[tid], q = red[64 + tid];
    float mean = s / M;
    float var = q / M - mean * mean;
    float sc = gamma[tid] / sqrtf(var + 1e-5f);
    ss[tid] = sc;
    ss[64 + tid] = beta[tid] - mean * sc;
  }
}

// bn+relu, f32 in-place (final output)
__global__ void k_bnrelu4(float4* __restrict__ buf, const float* __restrict__ ss, long total4) {
  __shared__ float s_ss[128];
  if (threadIdx.x < 128) s_ss[threadIdx.x] = ss[threadIdx.x];
  __syncthreads();
  long i = (long)blockIdx.x * blockDim.x + threadIdx.x;
  long stride = (long)gridDim.x * blockDim.x;
  for (long k = i; k < total4; k += stride) {
    float4 v = buf[k];
    int j0 = ((int)k & 15) * 4;
    v.x = fmaxf(fmaf(v.x, s_ss[j0 + 0], s_ss[64 + j0 + 0]), 0.f);
    v.y = fmaxf(fmaf(v.y, s_ss[j0 + 1], s_ss[64 + j0 + 1]), 0.f);
    v.z = fmaxf(fmaf(v.z, s_ss[j0 + 2], s_ss[64 + j0 + 2]), 0.f);
    v.w = fmaxf(fmaf(v.w, s_ss[j0 + 3], s_ss[64 + j0 + 3]), 0.f);
    buf[k] = v;
  }
}

// bn+relu, bf16 in -> bf16 out (h_pre -> h)
__global__ void k_bnrelu_b2b(const ushort4* __restrict__ in, ushort4* __restrict__ out,
                             const float* __restrict__ ss, long total4) {
  __shared__ float s_ss[128];
  if (threadIdx.x < 128) s_ss[threadIdx.x] = ss[threadIdx.x];
  __syncthreads();
  long i = (long)blockIdx.x * blockDim.x + threadIdx.x;
  long stride = (long)gridDim.x * blockDim.x;
  for (long k = i; k < total4; k += stride) {
    ushort4 v = in[k];
    int j0 = ((int)k & 15) * 4;
    ushort4 o;
    o.x = f2bf(fmaxf(fmaf(bf2f(v.x), s_ss[j0 + 0], s_ss[64 + j0 + 0]), 0.f));
    o.y = f2bf(fmaxf(fmaf(bf2f(v.y), s_ss[j0 + 1], s_ss[64 + j0 + 1]), 0.f));
    o.z = f2bf(fmaxf(fmaf(bf2f(v.z), s_ss[j0 + 2], s_ss[64 + j0 + 2]), 0.f));
    o.w = f2bf(fmaxf(fmaf(bf2f(v.w), s_ss[j0 + 3], s_ss[64 + j0 + 3]), 0.f));
    out[k] = o;
  }
}

extern "C" void kernel_launch(void* const* d_in, const int* in_sizes, int n_in,
                              void* d_out, int out_size, void* d_ws, size_t ws_size,
                              hipStream_t stream) {
  const float* x        = (const float*)d_in[0];
  const float* edge_w   = (const float*)d_in[1];
  const float* W_lin1   = (const float*)d_in[2];
  const float* W_self1  = (const float*)d_in[4];
  const float* gamma1   = (const float*)d_in[6];
  const float* beta1    = (const float*)d_in[7];
  const float* W_lin2   = (const float*)d_in[8];
  const float* W_self2  = (const float*)d_in[10];
  const float* gamma2   = (const float*)d_in[12];
  const float* beta2    = (const float*)d_in[13];
  const int* node_in    = (const int*)d_in[14];
  const int* node_out   = (const int*)d_in[15];
  const int* relation   = (const int*)d_in[16];

  int N = in_sizes[0] / 64;           // 50000
  int E = in_sizes[1];                // 800000
  int R = in_sizes[2] / (64 * 64);    // 8
  int NR = N * R;
  int NB = (NR + SCAN_CHUNK - 1) / SCAN_CHUNK;

  char* p = (char*)d_ws;
  auto alloc = [&](size_t bytes) { char* r = p; p += (bytes + 255) & ~(size_t)255; return r; };
  float* deg    = (float*)alloc(4ull * NR);
  int* cnt      = (int*)alloc(4ull * NR);
  int* rowptr   = (int*)alloc(4ull * (NR + 1));
  int* wptr     = (int*)alloc(4ull * NR);
  int* bsum     = (int*)alloc(4ull * NB);
  int* bpre     = (int*)alloc(4ull * NB);
  int2* ep      = (int2*)alloc(8ull * E);
  unsigned short* wb1 = (unsigned short*)alloc(2ull * (R + 1) * 64 * 64);
  unsigned short* wb2 = (unsigned short*)alloc(2ull * 2 * 64 * 64);
  float* s1     = (float*)alloc(4ull * N * 64);
  unsigned short* h_pre = (unsigned short*)alloc(2ull * N * 64);
  unsigned short* z = (unsigned short*)alloc(2ull * N * 64);
  float* s2     = (float*)alloc(4ull * N * 64);
  float* part   = (float*)alloc(4ull * GATHER_GRID * 128);
  float* ss1    = (float*)alloc(4ull * 128);
  float* ss2    = (float*)alloc(4ull * 128);

  // d_out upper region as scratch: y1 bf16 [0, 51.2MB), xb, hb after.
  unsigned short* y1 = (unsigned short*)d_out;
  unsigned short* xb = (unsigned short*)((char*)d_out + 2ull * R * N * 64);
  unsigned short* hb = xb + (size_t)N * 64;

  k_zero<<<512, 256, 0, stream>>>(deg, cnt, NR);
  k_count<<<1024, 256, 0, stream>>>(edge_w, node_out, relation, deg, cnt, E, R);
  k_scan1<<<NB, 256, 0, stream>>>(cnt, bsum, NR);
  k_scan2<<<1, 64, 0, stream>>>(bsum, bpre, &rowptr[NR], NB);
  k_scan3<<<NB, 256, 0, stream>>>(cnt, bpre, rowptr, wptr, NR);
  k_fill<<<1024, 256, 0, stream>>>(edge_w, node_out, node_in, relation, deg, wptr, ep, E, R);

  k_f2b<<<1024, 256, 0, stream>>>((const float4*)x, (ushort4*)xb, N * 64 / 4);
  k_packW<<<64, 256, 0, stream>>>(W_lin1, W_self1, W_lin2, W_self2, wb1, wb2, R);

  // layer 1
  int mblocks = (N + 63) / 64;
  k_gemm_mfma<<<mblocks, 256, 0, stream>>>(xb, N, wb1, R, y1, s1);
  k_gather1<<<GATHER_GRID, 256, 0, stream>>>(rowptr, ep, y1, s1, h_pre, part, N, R);
  k_bnstats<<<1, 1024, 0, stream>>>(part, GATHER_GRID, (float)N, gamma1, beta1, ss1);
  k_bnrelu_b2b<<<2048, 256, 0, stream>>>((const ushort4*)h_pre, (ushort4*)hb, ss1, (long)N * 64 / 4);

  // layer 2
  k_gemm_mfma<<<mblocks, 256, 0, stream>>>(hb, N, wb2, 1, z, s2);
  k_gather2<<<GATHER_GRID, 256, 0, stream>>>(rowptr, ep, z, s2, (float*)d_out, part, N, R);
  k_bnstats<<<1, 1024, 0, stream>>>(part, GATHER_GRID, (float)N * R, gamma2, beta2, ss2);
  k_bnrelu4<<<4096, 256, 0, stream>>>((float4*)d_out, ss2, (long)N * R * 64 / 4);
}